// Round 12
// baseline (9632.095 us; speedup 1.0000x reference)
//
#include <hip/hip_runtime.h>
#include <hip/hip_bf16.h>
#include <stdint.h>

// BayesGRU eval: T=512, B=64, D_IN=1024, D_H=1024.
// Round 12 = R11 transport/flags + Cb=32 geometry with LDS h/rh staging:
//   128 WGs: c-class wg<64 (u+cell+update), r-class wg>=64 (reset gate).
//   WG tile = 32 rows x 32 cols: idx=wg&63, v=idx>>1 (col-tile), rhalf=idx&1.
//   Each WG bypass-reads ONLY its 32 rows of h (64 KB) once -> LDS (swizzled),
//   waves ds_read fragments => h traffic 16->8 MB/step; rh staged likewise.
//   u-gate + all x-part weights streamed per step via CACHED loads (packed in
//   dispatch 1, read-only => replay-safe; same class as LDS weight loads).
// Transport rules (proven R3-R11): same-dispatch data = WT(sc0sc1) stores +
// bypass(sc0sc1) loads only. Flags: 64B lines, leader polls.
// H=fam0 q8 (c posts g=wg>>3); Rlo=fam1/Rhi=fam2 q4 (r posts by idx>>2).

#define T_STEPS 512
#define BATCH   64
#define DIN     1024
#define DH      1024
#define NWG     128
#define SLAB    65536            // B*DH elements (128KB bf16)

typedef __attribute__((ext_vector_type(8))) short bf16x8;
typedef __attribute__((ext_vector_type(4))) float f32x4;

static __device__ __forceinline__ unsigned short f2bf(float x) {
    union { float f; uint32_t u; } v; v.f = x;
    uint32_t u = v.u;
    return (unsigned short)((u + 0x7FFFu + ((u >> 16) & 1u)) >> 16);
}
static __device__ __forceinline__ float bf2f(unsigned short u) {
    union { uint32_t v; float f; } x; x.v = (uint32_t)u << 16; return x.f;
}
static __device__ __forceinline__ bf16x8 cvt8(float4 a, float4 b) {
    union { bf16x8 v; unsigned d[4]; } u;
    asm("v_cvt_pk_bf16_f32 %0, %1, %2" : "=v"(u.d[0]) : "v"(a.x), "v"(a.y));
    asm("v_cvt_pk_bf16_f32 %0, %1, %2" : "=v"(u.d[1]) : "v"(a.z), "v"(a.w));
    asm("v_cvt_pk_bf16_f32 %0, %1, %2" : "=v"(u.d[2]) : "v"(b.x), "v"(b.y));
    asm("v_cvt_pk_bf16_f32 %0, %1, %2" : "=v"(u.d[3]) : "v"(b.z), "v"(b.w));
    return u.v;
}

// ---- stale-immune transport (proven R3-R11) --------------------------------
static __device__ __forceinline__ void st_wt_u16(void* p, unsigned v) {
    asm volatile("global_store_short %0, %1, off sc0 sc1" :: "v"(p), "v"(v) : "memory");
}
static __device__ __forceinline__ bf16x8 ld_llc(const unsigned short* p) {
    bf16x8 r;
    asm volatile("global_load_dwordx4 %0, %1, off sc0 sc1" : "=v"(r) : "v"(p));
    return r;
}
static __device__ __forceinline__ void vwait0() {
    asm volatile("s_waitcnt vmcnt(0)" ::: "memory");
    __builtin_amdgcn_sched_barrier(0);   // rule #18
}

// ---- flag wait/post (verbatim R11) -----------------------------------------
static __device__ __forceinline__ void wait_fam(const int* cnt, int t, int fam, int quota) {
    const int* b = cnt + t * 128 + fam;
    for (;;) {
        int a0,a1,a2,a3,a4,a5,a6,a7;
        asm volatile("global_load_dword %0, %1, off sc0 sc1" : "=v"(a0) : "v"(b));
        asm volatile("global_load_dword %0, %1, off sc0 sc1" : "=v"(a1) : "v"(b+16));
        asm volatile("global_load_dword %0, %1, off sc0 sc1" : "=v"(a2) : "v"(b+32));
        asm volatile("global_load_dword %0, %1, off sc0 sc1" : "=v"(a3) : "v"(b+48));
        asm volatile("global_load_dword %0, %1, off sc0 sc1" : "=v"(a4) : "v"(b+64));
        asm volatile("global_load_dword %0, %1, off sc0 sc1" : "=v"(a5) : "v"(b+80));
        asm volatile("global_load_dword %0, %1, off sc0 sc1" : "=v"(a6) : "v"(b+96));
        asm volatile("global_load_dword %0, %1, off sc0 sc1" : "=v"(a7) : "v"(b+112));
        asm volatile("s_waitcnt vmcnt(0)" ::: "memory");
        __builtin_amdgcn_sched_barrier(0);
        if (a0>=quota && a1>=quota && a2>=quota && a3>=quota &&
            a4>=quota && a5>=quota && a6>=quota && a7>=quota) break;
        __builtin_amdgcn_s_sleep(2);
    }
}
static __device__ __forceinline__ void wg_wait(const int* cnt, int t, int fam, int quota) {
    if (threadIdx.x == 0) wait_fam(cnt, t, fam, quota);
    __syncthreads();
}
static __device__ __forceinline__ void post_fam(int* cnt, int t, int g, int fam) {
    __hip_atomic_fetch_add(cnt + t * 128 + g * 16 + fam, 1,
                           __ATOMIC_RELAXED, __HIP_MEMORY_SCOPE_AGENT);
}

// ---------------- weight packing (verbatim, verified rounds 1-11) -----------
// Wur: [kk=64][b=128][kg=4][col=16][8] (u cols: b<64, r cols: b>=64)
// Wc : [kk=64][b=64 ][kg=4][col=16][8], K order = [x | h].
__global__ __launch_bounds__(256) void gru_pack_weights(
    const float* __restrict__ wihu, const float* __restrict__ wihr,
    const float* __restrict__ wihc, const float* __restrict__ whhu,
    const float* __restrict__ whhr, const float* __restrict__ whhc,
    unsigned short* __restrict__ Wur, unsigned short* __restrict__ Wc)
{
    const int total = 3072 * 2048;
    for (int idx = blockIdx.x * 256 + threadIdx.x; idx < total; idx += gridDim.x * 256) {
        int n = idx >> 11;
        int k = idx & 2047;
        int j = n & 1023;
        float v;
        if (n < 1024)      v = (k < DIN) ? wihu[j*DIN + k] : whhu[j*DH + (k - DIN)];
        else if (n < 2048) v = (k < DIN) ? wihr[j*DIN + k] : whhr[j*DH + (k - DIN)];
        else               v = (k < DIN) ? wihc[j*DIN + k] : whhc[j*DH + (k - DIN)];
        unsigned short bv = f2bf(v);
        int kk = k >> 5, kg = (k >> 3) & 3, r = k & 7;
        if (n < 2048) {
            int b = n >> 4, col = n & 15;
            Wur[((((size_t)kk*128 + b)*4 + kg)*16 + col)*8 + r] = bv;
        } else {
            int nc = n - 2048, b = nc >> 4, col = nc & 15;
            Wc [((((size_t)kk*64 + b)*4 + kg)*16 + col)*8 + r] = bv;
        }
    }
}

// ---------------- emb fp32 -> bf16 (deep path) ------------------------------
__global__ __launch_bounds__(256) void gru_convert_x(
    const float* __restrict__ emb, unsigned short* __restrict__ xbf)
{
    size_t i = (size_t)blockIdx.x * 256 + threadIdx.x;
    float4 v = ((const float4*)emb)[i];
    ushort4 b;
    b.x = f2bf(v.x); b.y = f2bf(v.y); b.z = f2bf(v.z); b.w = f2bf(v.w);
    ((ushort4*)xbf)[i] = b;
}

// ---------------- init: hA[0] = bf16(h0), counters = 0 ----------------------
__global__ __launch_bounds__(256) void gru_init(
    const float* __restrict__ hx, unsigned short* __restrict__ hA,
    int* __restrict__ cnt)
{
    int i = blockIdx.x * 256 + threadIdx.x;   // 256x256 = 65536
    hA[i] = f2bf(hx[i]);
    cnt[i] = 0;
}

// ---------------- persistent GRU kernel -------------------------------------
__global__ __launch_bounds__(256, 1) void gru_persistent(
    const unsigned short* __restrict__ Wur, const unsigned short* __restrict__ Wc,
    const float* __restrict__ emb, const unsigned short* __restrict__ xbf,
    const float* __restrict__ hx,
    const float* __restrict__ bu, const float* __restrict__ br, const float* __restrict__ bc,
    unsigned short* __restrict__ hA, unsigned short* __restrict__ rh,
    float* __restrict__ out, int* __restrict__ cnt, int deep)
{
    __shared__ unsigned short W_s[32768];     // 64 KB class h-part weights (32 cols)
    __shared__ unsigned short hstage[32768];  // 64 KB staged h (then rh for c-class)

    const int wg    = blockIdx.x;
    const int tid   = threadIdx.x;
    const int lane  = tid & 63;
    const int wid   = tid >> 6;
    const int c15   = lane & 15;
    const int kg    = lane >> 4;
    const bool isC  = (wg < 64);
    const int idx   = wg & 63;
    const int v     = idx >> 1;               // col-tile [32v, 32v+32)
    const int rhalf = idx & 1;                // rows [32*rhalf, 32*rhalf+32)
    const int rt    = wid & 1;                // row-subtile of wave
    const int cs    = wid >> 1;               // col-subtile of wave
    const int mloc  = rt * 16;                // local row base (0 or 16)
    const int rowbase = rhalf * 32;
    const int colj  = v * 32 + cs * 16 + c15;

    // ---- class h-part weights -> LDS: layout [kk 0..31][cs2 0..1][512 shorts]
    for (int i = tid; i < 4096; i += 256) {   // 4096 uint4 = 64 KB
        int kk = i >> 7, rem = i & 127, cs2 = rem >> 6, q = rem & 63;
        const char* src = isC
            ? (const char*)Wc  + ((size_t)((kk + 32) * 64  + 2 * v + cs2)) * 1024 + q * 16
            : (const char*)Wur + ((size_t)((kk + 32) * 128 + 64 + 2 * v + cs2)) * 1024 + q * 16;
        ((uint4*)W_s)[i] = *(const uint4*)src;
    }
    __syncthreads();

    const float bu_ = isC ? bu[colj] : 0.f;
    const float bc_ = isC ? bc[colj] : 0.f;
    const float br_ = isC ? 0.f : br[colj];

    float hreg[4];
    if (isC) {
        #pragma unroll
        for (int i = 0; i < 4; ++i)
            hreg[i] = hx[(rowbase + mloc + kg * 4 + i) * DH + colj];
    }

    for (int t = 0; t < T_STEPS; ++t) {
        const int par = t & 1;
        const unsigned short* ha = hA + par * SLAB;

        f32x4 accA = {0.f,0.f,0.f,0.f};   // c: u-gate   | r: r-gate
        f32x4 accC = {0.f,0.f,0.f,0.f};   // c: cell

        // ---- x-parts (pre-wait; cached xbf or emb; streamed cached weights)
        {
            const int grow16 = rowbase + mloc + c15;    // A-frag row
            if (deep) {
                const unsigned short* xp =
                    xbf + ((size_t)t * BATCH + grow16) * DIN + kg * 8;
                #pragma unroll
                for (int kk = 0; kk < 32; ++kk) {
                    bf16x8 a = *(const bf16x8*)(xp + kk * 32);
                    if (isC) {
                        bf16x8 b0 = *(const bf16x8*)((const char*)Wur +
                            ((size_t)(kk * 128 + 2 * v + cs)) * 1024 + lane * 16);
                        accA = __builtin_amdgcn_mfma_f32_16x16x32_bf16(a, b0, accA, 0, 0, 0);
                        bf16x8 b1 = *(const bf16x8*)((const char*)Wc +
                            ((size_t)(kk * 64 + 2 * v + cs)) * 1024 + lane * 16);
                        accC = __builtin_amdgcn_mfma_f32_16x16x32_bf16(a, b1, accC, 0, 0, 0);
                    } else {
                        bf16x8 b0 = *(const bf16x8*)((const char*)Wur +
                            ((size_t)(kk * 128 + 64 + 2 * v + cs)) * 1024 + lane * 16);
                        accA = __builtin_amdgcn_mfma_f32_16x16x32_bf16(a, b0, accA, 0, 0, 0);
                    }
                }
            } else {
                const float* xp = emb + ((size_t)t * BATCH + grow16) * DIN + kg * 8;
                #pragma unroll
                for (int kk = 0; kk < 32; ++kk) {
                    float4 fa = *(const float4*)(xp + kk * 32);
                    float4 fb = *(const float4*)(xp + kk * 32 + 4);
                    bf16x8 a = cvt8(fa, fb);
                    if (isC) {
                        bf16x8 b0 = *(const bf16x8*)((const char*)Wur +
                            ((size_t)(kk * 128 + 2 * v + cs)) * 1024 + lane * 16);
                        accA = __builtin_amdgcn_mfma_f32_16x16x32_bf16(a, b0, accA, 0, 0, 0);
                        bf16x8 b1 = *(const bf16x8*)((const char*)Wc +
                            ((size_t)(kk * 64 + 2 * v + cs)) * 1024 + lane * 16);
                        accC = __builtin_amdgcn_mfma_f32_16x16x32_bf16(a, b1, accC, 0, 0, 0);
                    } else {
                        bf16x8 b0 = *(const bf16x8*)((const char*)Wur +
                            ((size_t)(kk * 128 + 64 + 2 * v + cs)) * 1024 + lane * 16);
                        accA = __builtin_amdgcn_mfma_f32_16x16x32_bf16(a, b0, accA, 0, 0, 0);
                    }
                }
            }
        }

        // ---- wait h(t-1), stage this WG's 32 rows of h -> LDS (swizzled) ----
        if (t) wg_wait(cnt, t - 1, 0, 8);
        {
            const char* src = (const char*)ha + (size_t)rowbase * 2048;  // 64 KB contig
            bf16x8 tmp[16];
            #pragma unroll
            for (int j = 0; j < 16; ++j)
                tmp[j] = ld_llc((const unsigned short*)(src + tid * 16 + j * 4096));
            vwait0();
            #pragma unroll
            for (int j = 0; j < 16; ++j) {
                int L = tid * 16 + j * 4096;
                int lr = L >> 11;
                *(bf16x8*)((char*)hstage + (L ^ ((lr & 7) << 4))) = tmp[j];
            }
        }
        __syncthreads();

        // ---- h-part matmul (A from LDS stage; u: streamed B / r: LDS B) ----
        {
            const int lr = mloc + c15;
            const int sw = (lr & 7) << 4;
            #pragma unroll
            for (int kk = 0; kk < 32; ++kk) {
                bf16x8 a = *(const bf16x8*)((const char*)hstage +
                               ((lr * 2048 + kk * 64 + kg * 16) ^ sw));
                if (isC) {
                    bf16x8 b0 = *(const bf16x8*)((const char*)Wur +
                        ((size_t)((kk + 32) * 128 + 2 * v + cs)) * 1024 + lane * 16);
                    accA = __builtin_amdgcn_mfma_f32_16x16x32_bf16(a, b0, accA, 0, 0, 0);
                } else {
                    bf16x8 b0 = *(const bf16x8*)(W_s + (kk * 2 + cs) * 512 + lane * 8);
                    accA = __builtin_amdgcn_mfma_f32_16x16x32_bf16(a, b0, accA, 0, 0, 0);
                }
            }
        }

        if (isC) {
            float ureg[4];
            #pragma unroll
            for (int i = 0; i < 4; ++i)
                ureg[i] = 1.f / (1.f + __expf(-(accA[i] + bu_)));

            __syncthreads();   // all waves done reading hstage(h) before rh overwrite

            // ---- rh halves: wait, stage 32KB, matmul (B from LDS W_s) ----
            #pragma unroll 1
            for (int half = 0; half < 2; ++half) {
                wg_wait(cnt, t, 1 + half, 4);
                {
                    const int lr = tid >> 3, seg = tid & 7;
                    const char* sp = (const char*)rh +
                        ((size_t)(rowbase + lr)) * 2048 + half * 1024 + seg * 128;
                    bf16x8 tmp[8];
                    #pragma unroll
                    for (int j = 0; j < 8; ++j)
                        tmp[j] = ld_llc((const unsigned short*)(sp + j * 16));
                    vwait0();
                    #pragma unroll
                    for (int j = 0; j < 8; ++j) {
                        int L = lr * 2048 + half * 1024 + seg * 128 + j * 16;
                        *(bf16x8*)((char*)hstage + (L ^ ((lr & 7) << 4))) = tmp[j];
                    }
                }
                __syncthreads();
                {
                    const int lr = mloc + c15;
                    const int sw = (lr & 7) << 4;
                    #pragma unroll
                    for (int kk2 = 0; kk2 < 16; ++kk2) {
                        int kk = half * 16 + kk2;
                        bf16x8 a = *(const bf16x8*)((const char*)hstage +
                                       ((lr * 2048 + kk * 64 + kg * 16) ^ sw));
                        bf16x8 b0 = *(const bf16x8*)(W_s + (kk * 2 + cs) * 512 + lane * 8);
                        accC = __builtin_amdgcn_mfma_f32_16x16x32_bf16(a, b0, accC, 0, 0, 0);
                    }
                }
            }

            // ---- update + publish h ----
            float* out_t = out + (size_t)t * SLAB;
            unsigned short* hnxt = hA + (par ^ 1) * SLAB;
            #pragma unroll
            for (int i = 0; i < 4; ++i) {
                int grow = rowbase + mloc + kg * 4 + i;
                float pre = accC[i] + bc_;
                float e   = __expf(2.f * pre);
                float cel = 1.f - 2.f / (e + 1.f);          // tanh
                float hn  = (1.f - ureg[i]) * hreg[i] + ureg[i] * cel;
                hreg[i] = hn;
                out_t[grow * DH + colj] = hn;               // normal (write-only)
                st_wt_u16(hnxt + grow * DH + colj, (unsigned)f2bf(hn));
                if (t == T_STEPS - 1)
                    out[(size_t)T_STEPS * SLAB + grow * DH + colj] = hn;
            }
            asm volatile("s_waitcnt vmcnt(0)" ::: "memory");
            __syncthreads();
            if (tid == 0) post_fam(cnt, t, wg >> 3, 0);
        } else {
            // ---- r: sigmoid, rst*h from staged h, publish rh ----
            #pragma unroll
            for (int i = 0; i < 4; ++i) {
                int lr2  = mloc + kg * 4 + i;
                int B    = lr2 * 2048 + colj * 2;
                unsigned short hp = *(const unsigned short*)((const char*)hstage +
                                        (B ^ ((lr2 & 7) << 4)));
                int grow = rowbase + lr2;
                float s = 1.f / (1.f + __expf(-(accA[i] + br_)));
                st_wt_u16(rh + grow * DH + colj, (unsigned)f2bf(s * bf2f(hp)));
            }
            asm volatile("s_waitcnt vmcnt(0)" ::: "memory");
            __syncthreads();
            if (tid == 0) {
                if (idx < 32) post_fam(cnt, t, idx >> 2, 1);          // cols < 512
                else          post_fam(cnt, t, (idx - 32) >> 2, 2);   // cols >= 512
            }
        }
    }
}

// ---------------- host launch ----------------------------------------------
extern "C" void kernel_launch(void* const* d_in, const int* in_sizes, int n_in,
                              void* d_out, int out_size, void* d_ws, size_t ws_size,
                              hipStream_t stream)
{
    const float* emb  = (const float*)d_in[0];
    const float* hx   = (const float*)d_in[1];
    const float* wihu = (const float*)d_in[2];
    const float* wihr = (const float*)d_in[3];
    const float* wihc = (const float*)d_in[4];
    const float* whhu = (const float*)d_in[5];
    const float* whhr = (const float*)d_in[6];
    const float* whhc = (const float*)d_in[7];
    const float* bu   = (const float*)d_in[8];
    const float* br   = (const float*)d_in[9];
    const float* bc   = (const float*)d_in[10];
    float* out = (float*)d_out;
    char*  ws  = (char*)d_ws;

    // ws layout (bytes) — identical to R11:
    unsigned short* Wur = (unsigned short*)(ws + 0);          // 8 MiB
    unsigned short* Wc  = (unsigned short*)(ws + 8388608);    // 4 MiB
    int*            cnt = (int*)(ws + 12582912);              // 256 KiB flag lines
    unsigned short* hA  = (unsigned short*)(ws + 12845056);   // 256 KiB (2 slabs)
    unsigned short* rhb = (unsigned short*)(ws + 13107200);   // 128 KiB
    unsigned short* xbf = (unsigned short*)(ws + 16777216);   // 64 MiB (deep)
    const int deep = (ws_size >= 83886080ull) ? 1 : 0;

    gru_pack_weights<<<1024, 256, 0, stream>>>(wihu, wihr, wihc, whhu, whhr, whhc, Wur, Wc);
    if (deep) gru_convert_x<<<32768, 256, 0, stream>>>(emb, xbf);
    gru_init<<<256, 256, 0, stream>>>(hx, hA, cnt);
    gru_persistent<<<NWG, 256, 0, stream>>>(Wur, Wc, emb, xbf, hx, bu, br, bc,
                                            hA, rhb, out, cnt, deep);
}